// Round 6
// baseline (429.110 us; speedup 1.0000x reference)
//
#include <hip/hip_runtime.h>
#include <stdint.h>

#define BB 32
#define CC 256
#define HH 56
#define WW 56
#define TAPS 9
#define NCONV 3
#define BN_EPS 1e-5f

typedef int int4v  __attribute__((ext_vector_type(4)));
typedef int int16v __attribute__((ext_vector_type(16)));

// v_mfma_i32_32x32x32_i8: A 4 VGPR (16 i8), B 4 VGPR, C/D 16 VGPR.
#define MFMA_I8(accv, av, bv) \
    asm("v_mfma_i32_32x32x32_i8 %0, %1, %2, %0" : "+v"(accv) : "v"(av), "v"(bv))

// ---------------- workspace layout (bytes) ----------------
#define ACT8_BYTES   ((size_t)BB * HH * WW * CC)
#define WPACK_BYTES  ((size_t)NCONV * 8 * 4 * TAPS * 2 * 64 * 16)

// LDS act tile: ch-half planes, px stride 32B -> conflict-free ds_read_b128.
// addr = ch*L_CH + r*L_ROW + c*L_PX + h16*16 ; 4 rows x 58 cols x 2 planes.
#define L_PX   32
#define L_ROW  (58 * L_PX)        // 1856
#define L_CH   (4 * L_ROW)        // 7424
#define L_BUF  (2 * L_CH)         // 14848 per buffer
#define NSTU   (4 * 58 * 4)       // 928 16B staging units per tile

// act8[n][h][w][c] = sign(x + bias0) in i8. LDS transpose for coalescing.
__global__ __launch_bounds__(256) void pack_act8_kernel(
    const float* __restrict__ x, const float* __restrict__ bias0,
    int8_t* __restrict__ act8)
{
    __shared__ int8_t ldsT[56 * 260];
    const int tid = threadIdx.x;
    const int h = blockIdx.x % HH, n = blockIdx.x / HH;
    const int w = tid & 63;
    const int cq = tid >> 6;
    if (w < WW) {
        #pragma unroll 4
        for (int cc = 0; cc < 64; ++cc) {
            const int c = cc * 4 + cq;
            const float v = x[((size_t)(n * CC + c) * HH + h) * WW + w] + bias0[c];
            ldsT[w * 260 + c] = (v > 0.f) ? (int8_t)1 : ((v < 0.f) ? (int8_t)-1 : (int8_t)0);
        }
    }
    __syncthreads();
    uint32_t* o32 = (uint32_t*)(act8 + (size_t)(n * HH + h) * WW * CC);
    #pragma unroll
    for (int i = 0; i < 14; ++i) {
        const int flat = i * 1024 + tid * 4;
        const int ww = flat >> 8, c4 = flat & 255;
        o32[flat >> 2] = *(const uint32_t*)(ldsT + ww * 260 + c4);
    }
}

// per-output-channel scale = mean |w|. one wave per (j,o).
__global__ __launch_bounds__(64) void pack_scales_kernel(
    const float* __restrict__ w0, const float* __restrict__ w1,
    const float* __restrict__ w2, float* __restrict__ scales)
{
    const int j = blockIdx.x >> 8;
    const int o = blockIdx.x & 255;
    const float* wp = (j == 0) ? w0 : ((j == 1) ? w1 : w2);
    const int lane = threadIdx.x;
    const float* wo = wp + (size_t)o * CC * TAPS;
    float s = 0.f;
    for (int k = lane; k < CC * TAPS; k += 64) s += fabsf(wo[k]);
    #pragma unroll
    for (int d = 32; d > 0; d >>= 1) s += __shfl_xor(s, d);
    if (lane == 0) scales[j * CC + o] = s * (1.0f / (float)(CC * TAPS));
}

// weight signs in exact A-fragment order (same as round 5, verified).
__global__ __launch_bounds__(256) void pack_wpack_kernel(
    const float* __restrict__ w0, const float* __restrict__ w1,
    const float* __restrict__ w2, int8_t* __restrict__ wpack)
{
    const int j  = blockIdx.x >> 3;
    const int ot = blockIdx.x & 7;
    const float* wp = (j == 0) ? w0 : ((j == 1) ? w1 : w2);
    const int tid = threadIdx.x;
    #pragma unroll 1
    for (int it = 0; it < 18; ++it) {
        const int e = it * 256 + tid;
        const int g = e / 1152;
        const int rem = e - g * 1152;
        const int tt = rem >> 7;
        const int rem2 = rem & 127;
        const int ch = rem2 >> 6;
        const int ln = rem2 & 63;
        const int o = ot * 32 + (ln & 31);
        const int cbase = g * 64 + ch * 32 + ((ln >> 5) & 1) * 16;
        int8_t bytes[16];
        #pragma unroll
        for (int b = 0; b < 16; ++b) {
            const float v = wp[((size_t)o * CC + cbase + b) * TAPS + tt];
            bytes[b] = (v > 0.f) ? (int8_t)1 : ((v < 0.f) ? (int8_t)-1 : (int8_t)0);
        }
        *(int4v*)(wpack + ((size_t)(j * 8 + ot) * 4608 + e) * 16) = *(int4v*)bytes;
    }
}

// epilogue constants per o: {A, beta - rmean*A + bias1, prelu_a, bias2}
__global__ __launch_bounds__(256) void pack_epack_kernel(
    const float* __restrict__ gamma, const float* __restrict__ beta,
    const float* __restrict__ rmean, const float* __restrict__ rvar,
    const float* __restrict__ bias1, const float* __restrict__ prelu_a,
    const float* __restrict__ bias2, float* __restrict__ epack)
{
    const int o = threadIdx.x;
    const float A = gamma[o] * rsqrtf(rvar[o] + BN_EPS);
    epack[o * 4 + 0] = A;
    epack[o * 4 + 1] = beta[o] - rmean[o] * A + bias1[o];
    epack[o * 4 + 2] = prelu_a[o];
    epack[o * 4 + 3] = bias2[o];
}

// main: i8 MFMA implicit conv, double-buffered LDS staging.
// 12 phases = (j,g); per phase: prefetch next tile to regs, 18 ksteps x
// {2 A dwordx4 (L2), 2 B ds_read_b128 (conflict-free), 4 mfma}, ds_write
// next tile, 1 barrier. XCD-swizzled blockIdx for act8 L2 residency.
__global__ __launch_bounds__(256) void conv_mfma_kernel(
    const int8_t* __restrict__ act8, const int8_t* __restrict__ wpack,
    const float* __restrict__ scales, const float* __restrict__ epack,
    const float* __restrict__ x, float* __restrict__ out)
{
    __shared__ __align__(16) int8_t lds[2][L_BUF];
    const int tid  = threadIdx.x;
    const int lane = tid & 63;
    const int wv   = __builtin_amdgcn_readfirstlane(tid >> 6);
    // bijective XCD swizzle: 1568 = 8 * 196
    const int bid  = blockIdx.x;
    const int swz  = (bid & 7) * 196 + (bid >> 3);
    const int pxblk = swz % 49;
    const int n     = swz / 49;
    const int px0   = pxblk * 64;
    const int h_lo  = px0 / WW;           // 64-px strip spans rows h_lo, h_lo+1

    // per-lane LDS byte bases for the two B px-tiles
    int boff[2];
    #pragma unroll
    for (int pt = 0; pt < 2; ++pt) {
        const int p = px0 + pt * 32 + (lane & 31);
        const int hl = p / WW, wl = p % WW;
        boff[pt] = (hl - h_lo) * L_ROW + wl * L_PX + ((lane >> 5) & 1) * 16;
    }

    // staging precompute: unit u = tid + k*256 covers 4 rows x 58 cols x 4 q
    int st_hr[4], st_wc[4], st_q[4], st_lds[4];
    bool st_v[4], st_act[4];
    #pragma unroll
    for (int k = 0; k < 4; ++k) {
        const int u = tid + k * 256;
        st_act[k] = (u < NSTU);
        const int r = u / 232;
        const int rem = u - r * 232;
        const int c = rem >> 2, q = rem & 3;
        st_q[k]  = q;
        st_hr[k] = h_lo - 1 + r;
        st_wc[k] = c - 1;
        st_v[k]  = st_act[k] && (st_hr[k] >= 0) && (st_hr[k] < HH)
                             && (st_wc[k] >= 0) && (st_wc[k] < WW);
        st_lds[k] = (q >> 1) * L_CH + r * L_ROW + c * L_PX + (q & 1) * 16;
    }
    const size_t nbase = (size_t)n * HH;

    float fsum[2][2][16];
    #pragma unroll
    for (int q = 0; q < 2; ++q)
        #pragma unroll
        for (int pt = 0; pt < 2; ++pt)
            #pragma unroll
            for (int r = 0; r < 16; ++r) fsum[q][pt][r] = 0.f;

    int16v acc[2][2];
    int4v sreg[4];

    // ---- stage phase 0 ----
    {
        #pragma unroll
        for (int k = 0; k < 4; ++k) {
            int4v v = {0, 0, 0, 0};
            if (st_v[k])   // phase 0: j=0 (no roll), g=0
                v = *(const int4v*)(act8 +
                    (((nbase + st_hr[k]) * WW + st_wc[k]) << 8) + st_q[k] * 16);
            sreg[k] = v;
        }
        #pragma unroll
        for (int k = 0; k < 4; ++k)
            if (st_act[k]) *(int4v*)(&lds[0][st_lds[k]]) = sreg[k];
    }
    __syncthreads();

    #pragma unroll 1
    for (int ph = 0; ph < 12; ++ph) {
        const int j = ph >> 2, g = ph & 3;
        if ((ph & 3) == 0) {
            #pragma unroll
            for (int q = 0; q < 2; ++q)
                #pragma unroll
                for (int pt = 0; pt < 2; ++pt)
                    #pragma unroll
                    for (int r = 0; r < 16; ++r) acc[q][pt][r] = 0;
        }

        // ---- prefetch next phase tile into regs (GATHER roll) ----
        if (ph < 11) {
            const int ph2 = ph + 1;
            const int j2 = ph2 >> 2, g2 = ph2 & 3;
            const int amt2 = (j2 == 0) ? 0 : ((j2 == 1) ? 1 : 3);
            const int rH = (g2 == 0) ? -amt2 : ((g2 == 1) ? amt2 : 0);
            const int rW = (g2 == 2) ? -amt2 : ((g2 == 3) ? amt2 : 0);
            #pragma unroll
            for (int k = 0; k < 4; ++k) {
                int4v v = {0, 0, 0, 0};
                if (st_v[k]) {
                    int hs = st_hr[k] + rH;
                    if (hs < 0) hs += HH; else if (hs >= HH) hs -= HH;
                    int ws = st_wc[k] + rW;
                    if (ws < 0) ws += WW; else if (ws >= WW) ws -= WW;
                    v = *(const int4v*)(act8 +
                        (((nbase + hs) * WW + ws) << 8) + g2 * 64 + st_q[k] * 16);
                }
                sreg[k] = v;
            }
        }

        // ---- compute current phase: 18 ksteps x 4 MFMA ----
        const int8_t* L = lds[ph & 1];
        const int8_t* wbase = wpack
            + ((size_t)((j * 8 + wv * 2) * 4 + g) * 18) * 1024 + lane * 16;
        __builtin_amdgcn_s_setprio(1);
        #pragma unroll
        for (int t = 0; t < TAPS; ++t) {
            #pragma unroll
            for (int ch = 0; ch < 2; ++ch) {
                const int koff = (t * 2 + ch) * 1024;
                const int4v a0 = *(const int4v*)(wbase + koff);
                const int4v a1 = *(const int4v*)(wbase + 73728 + koff);
                const int imm = ch * L_CH + (t / 3) * L_ROW + (t % 3) * L_PX;
                const int4v b0 = *(const int4v*)(L + boff[0] + imm);
                const int4v b1 = *(const int4v*)(L + boff[1] + imm);
                MFMA_I8(acc[0][0], a0, b0);
                MFMA_I8(acc[0][1], a0, b1);
                MFMA_I8(acc[1][0], a1, b0);
                MFMA_I8(acc[1][1], a1, b1);
            }
        }
        __builtin_amdgcn_s_setprio(0);

        // ---- write next tile to other buffer ----
        if (ph < 11) {
            int8_t* Ln = lds[(ph + 1) & 1];
            #pragma unroll
            for (int k = 0; k < 4; ++k)
                if (st_act[k]) *(int4v*)(Ln + st_lds[k]) = sreg[k];
        }

        // ---- fold at end of each j ----
        if ((ph & 3) == 3) {
            const float* scj = scales + j * CC + wv * 64;
            #pragma unroll
            for (int q = 0; q < 2; ++q) {
                #pragma unroll
                for (int r = 0; r < 16; ++r) {
                    const int rb = q * 32 + (r & 3) + 8 * (r >> 2);
                    const float slo = scj[rb], shi = scj[rb + 4];
                    const float sc = (lane & 32) ? shi : slo;
                    fsum[q][0][r] += sc * (float)acc[q][0][r];
                    fsum[q][1][r] += sc * (float)acc[q][1][r];
                }
            }
        }
        __syncthreads();
    }

    // epilogue: BN + residual + PReLU (D layout: col=lane&31, row=(r&3)+8*(r>>2)+4*(lane>>5))
    const int voff = (lane & 31) + ((lane >> 5) & 1) * (4 * HH * WW);
    #pragma unroll
    for (int q = 0; q < 2; ++q) {
        #pragma unroll
        for (int r = 0; r < 16; ++r) {
            const int o_lo = wv * 64 + q * 32 + (r & 3) + 8 * (r >> 2);
            const float* elo = epack + o_lo * 4;
            const float* ehi = epack + (o_lo + 4) * 4;
            const bool hi = (lane & 32) != 0;
            const float e0 = hi ? ehi[0] : elo[0];
            const float e1 = hi ? ehi[1] : elo[1];
            const float e2 = hi ? ehi[2] : elo[2];
            const float e3 = hi ? ehi[3] : elo[3];
            const size_t base = ((size_t)n * CC + o_lo) * (HH * WW) + px0;
            #pragma unroll
            for (int pt = 0; pt < 2; ++pt) {
                const size_t off = base + pt * 32 + voff;
                float v = fsum[q][pt][r] * e0 + e1 + x[off];
                v = (v > 0.f) ? v : e2 * v;
                out[off] = v + e3;
            }
        }
    }
}

// ===========================================================================
extern "C" void kernel_launch(void* const* d_in, const int* in_sizes, int n_in,
                              void* d_out, int out_size, void* d_ws, size_t ws_size,
                              hipStream_t stream) {
    const float* x       = (const float*)d_in[0];
    const float* bias0   = (const float*)d_in[1];
    const float* w0      = (const float*)d_in[2];
    const float* w1      = (const float*)d_in[3];
    const float* w2      = (const float*)d_in[4];
    const float* gamma   = (const float*)d_in[5];
    const float* beta    = (const float*)d_in[6];
    const float* rmean   = (const float*)d_in[7];
    const float* rvar    = (const float*)d_in[8];
    const float* bias1   = (const float*)d_in[9];
    const float* prelu_a = (const float*)d_in[10];
    const float* bias2   = (const float*)d_in[11];
    float* out = (float*)d_out;

    int8_t* act8   = (int8_t*)d_ws;
    int8_t* wpack  = act8 + ACT8_BYTES;
    float*  scales = (float*)(wpack + WPACK_BYTES);
    float*  epack  = scales + NCONV * CC;

    pack_act8_kernel<<<dim3(BB * HH), dim3(256), 0, stream>>>(x, bias0, act8);
    pack_scales_kernel<<<dim3(NCONV * CC), dim3(64), 0, stream>>>(w0, w1, w2, scales);
    pack_wpack_kernel<<<dim3(NCONV * 8), dim3(256), 0, stream>>>(w0, w1, w2, wpack);
    pack_epack_kernel<<<dim3(1), dim3(256), 0, stream>>>(
        gamma, beta, rmean, rvar, bias1, prelu_a, bias2, epack);
    conv_mfma_kernel<<<dim3(BB * 49), dim3(256), 0, stream>>>(
        act8, wpack, scales, epack, x, out);
}

// Round 7
// 275.210 us; speedup vs baseline: 1.5592x; 1.5592x over previous
//
#include <hip/hip_runtime.h>
#include <stdint.h>

#define BB 32
#define CC 256
#define HH 56
#define WW 56
#define TAPS 9
#define NCONV 3
#define BN_EPS 1e-5f

typedef int int4v  __attribute__((ext_vector_type(4)));
typedef int int16v __attribute__((ext_vector_type(16)));

// v_mfma_i32_32x32x32_i8: A 4 VGPR (16 i8), B 4 VGPR, C/D 16 VGPR.
#define MFMA_I8(accv, av, bv) \
    asm("v_mfma_i32_32x32x32_i8 %0, %1, %2, %0" : "+v"(accv) : "v"(av), "v"(bv))

// ---------------- workspace layout (bytes) ----------------
#define ACT8_BYTES   ((size_t)BB * HH * WW * CC)
#define WPACK_BYTES  ((size_t)NCONV * 8 * 4 * TAPS * 2 * 64 * 16)

// LDS act tile: ch-half planes, px stride 32B.
#define L_PX   32
#define L_ROW  (58 * L_PX)        // 1856
#define L_CH   (4 * L_ROW)        // 7424
#define L_BUF  (2 * L_CH)         // 14848 per buffer
#define NSTU   (4 * 58 * 4)       // 928 16B staging units per tile

// act8[n][h][w][c] = sign(x + bias0) in i8. LDS transpose for coalescing.
__global__ __launch_bounds__(256) void pack_act8_kernel(
    const float* __restrict__ x, const float* __restrict__ bias0,
    int8_t* __restrict__ act8)
{
    __shared__ int8_t ldsT[56 * 260];
    const int tid = threadIdx.x;
    const int h = blockIdx.x % HH, n = blockIdx.x / HH;
    const int w = tid & 63;
    const int cq = tid >> 6;
    if (w < WW) {
        #pragma unroll 4
        for (int cc = 0; cc < 64; ++cc) {
            const int c = cc * 4 + cq;
            const float v = x[((size_t)(n * CC + c) * HH + h) * WW + w] + bias0[c];
            ldsT[w * 260 + c] = (v > 0.f) ? (int8_t)1 : ((v < 0.f) ? (int8_t)-1 : (int8_t)0);
        }
    }
    __syncthreads();
    uint32_t* o32 = (uint32_t*)(act8 + (size_t)(n * HH + h) * WW * CC);
    #pragma unroll
    for (int i = 0; i < 14; ++i) {
        const int flat = i * 1024 + tid * 4;
        const int ww = flat >> 8, c4 = flat & 255;
        o32[flat >> 2] = *(const uint32_t*)(ldsT + ww * 260 + c4);
    }
}

// per-output-channel scale = mean |w| (one wave per (j,o)); epack fused in.
__global__ __launch_bounds__(64) void pack_scales_kernel(
    const float* __restrict__ w0, const float* __restrict__ w1,
    const float* __restrict__ w2, float* __restrict__ scales,
    const float* __restrict__ gamma, const float* __restrict__ beta,
    const float* __restrict__ rmean, const float* __restrict__ rvar,
    const float* __restrict__ bias1, const float* __restrict__ prelu_a,
    const float* __restrict__ bias2, float* __restrict__ epack)
{
    const int j = blockIdx.x >> 8;
    const int o = blockIdx.x & 255;
    const float* wp = (j == 0) ? w0 : ((j == 1) ? w1 : w2);
    const int lane = threadIdx.x;
    const float* wo = wp + (size_t)o * CC * TAPS;
    float s = 0.f;
    for (int k = lane; k < CC * TAPS; k += 64) s += fabsf(wo[k]);
    #pragma unroll
    for (int d = 32; d > 0; d >>= 1) s += __shfl_xor(s, d);
    if (lane == 0) scales[j * CC + o] = s * (1.0f / (float)(CC * TAPS));
    if (j == 0 && lane == 0) {
        const float A = gamma[o] * rsqrtf(rvar[o] + BN_EPS);
        epack[o * 4 + 0] = A;
        epack[o * 4 + 1] = beta[o] - rmean[o] * A + bias1[o];
        epack[o * 4 + 2] = prelu_a[o];
        epack[o * 4 + 3] = bias2[o];
    }
}

// weight signs in exact A-fragment order (verified r5/r6).
__global__ __launch_bounds__(256) void pack_wpack_kernel(
    const float* __restrict__ w0, const float* __restrict__ w1,
    const float* __restrict__ w2, int8_t* __restrict__ wpack)
{
    const int j  = blockIdx.x >> 3;
    const int ot = blockIdx.x & 7;
    const float* wp = (j == 0) ? w0 : ((j == 1) ? w1 : w2);
    const int tid = threadIdx.x;
    #pragma unroll 1
    for (int it = 0; it < 18; ++it) {
        const int e = it * 256 + tid;
        const int g = e / 1152;
        const int rem = e - g * 1152;
        const int tt = rem >> 7;
        const int rem2 = rem & 127;
        const int ch = rem2 >> 6;
        const int ln = rem2 & 63;
        const int o = ot * 32 + (ln & 31);
        const int cbase = g * 64 + ch * 32 + ((ln >> 5) & 1) * 16;
        int8_t bytes[16];
        #pragma unroll
        for (int b = 0; b < 16; ++b) {
            const float v = wp[((size_t)o * CC + cbase + b) * TAPS + tt];
            bytes[b] = (v > 0.f) ? (int8_t)1 : ((v < 0.f) ? (int8_t)-1 : (int8_t)0);
        }
        *(int4v*)(wpack + ((size_t)(j * 8 + ot) * 4608 + e) * 16) = *(int4v*)bytes;
    }
}

// main: i8 MFMA implicit conv; dbuf LDS staging; depth-3 SW-pipelined A/B
// register ring inside each phase (loads consumed 12 MFMAs later).
__global__ __launch_bounds__(256) void conv_mfma_kernel(
    const int8_t* __restrict__ act8, const int8_t* __restrict__ wpack,
    const float* __restrict__ scales, const float* __restrict__ epack,
    const float* __restrict__ x, float* __restrict__ out)
{
    __shared__ __align__(16) int8_t lds[2][L_BUF];
    const int tid  = threadIdx.x;
    const int lane = tid & 63;
    const int wv   = __builtin_amdgcn_readfirstlane(tid >> 6);
    const int bid  = blockIdx.x;
    const int swz  = (bid & 7) * 196 + (bid >> 3);   // bijective: 1568 = 8*196
    const int pxblk = swz % 49;
    const int n     = swz / 49;
    const int px0   = pxblk * 64;
    const int h_lo  = px0 / WW;

    int boff[2];
    #pragma unroll
    for (int pt = 0; pt < 2; ++pt) {
        const int p = px0 + pt * 32 + (lane & 31);
        const int hl = p / WW, wl = p % WW;
        boff[pt] = (hl - h_lo) * L_ROW + wl * L_PX + ((lane >> 5) & 1) * 16;
    }
    const size_t nbase = (size_t)n * HH;

    float fsum[2][2][16];
    #pragma unroll
    for (int q = 0; q < 2; ++q)
        #pragma unroll
        for (int pt = 0; pt < 2; ++pt)
            #pragma unroll
            for (int r = 0; r < 16; ++r) fsum[q][pt][r] = 0.f;

    int16v acc[2][2];
    int4v sreg[4];

    // staging helpers (addresses recomputed per call; VALU is idle)
    auto stage_load = [&](int rH, int rW, int gg) {
        #pragma unroll
        for (int k = 0; k < 4; ++k) {
            const int u = tid + k * 256;
            int4v v = {0, 0, 0, 0};
            if (u < NSTU) {
                const int r = u / 232;
                const int rem = u - r * 232;
                const int c = rem >> 2, q = rem & 3;
                const int hr = h_lo - 1 + r, wc = c - 1;
                if (hr >= 0 && hr < HH && wc >= 0 && wc < WW) {
                    int hs = hr + rH; if (hs < 0) hs += HH; else if (hs >= HH) hs -= HH;
                    int ws = wc + rW; if (ws < 0) ws += WW; else if (ws >= WW) ws -= WW;
                    v = *(const int4v*)(act8 +
                        (((nbase + hs) * WW + ws) << 8) + gg * 64 + q * 16);
                }
            }
            sreg[k] = v;
        }
    };
    auto stage_write = [&](int8_t* Ln) {
        #pragma unroll
        for (int k = 0; k < 4; ++k) {
            const int u = tid + k * 256;
            if (u < NSTU) {
                const int r = u / 232;
                const int rem = u - r * 232;
                const int c = rem >> 2, q = rem & 3;
                *(int4v*)(Ln + (q >> 1) * L_CH + r * L_ROW + c * L_PX + (q & 1) * 16) = sreg[k];
            }
        }
    };

    // ---- stage phase 0 (j=0 no roll, g=0) ----
    stage_load(0, 0, 0);
    stage_write(&lds[0][0]);
    __syncthreads();

    #pragma unroll 1
    for (int ph = 0; ph < 12; ++ph) {
        const int j = ph >> 2, g = ph & 3;
        if ((ph & 3) == 0) {
            #pragma unroll
            for (int q = 0; q < 2; ++q)
                #pragma unroll
                for (int pt = 0; pt < 2; ++pt)
                    #pragma unroll
                    for (int r = 0; r < 16; ++r) acc[q][pt][r] = 0;
        }

        // prefetch next phase tile into regs (GATHER roll: dest = src[idx-amt])
        if (ph < 11) {
            const int ph2 = ph + 1;
            const int j2 = ph2 >> 2, g2 = ph2 & 3;
            const int amt2 = (j2 == 0) ? 0 : ((j2 == 1) ? 1 : 3);
            const int rH = (g2 == 0) ? -amt2 : ((g2 == 1) ? amt2 : 0);
            const int rW = (g2 == 2) ? -amt2 : ((g2 == 3) ? amt2 : 0);
            stage_load(rH, rW, g2);
        }

        const int8_t* L = &lds[ph & 1][0];
        const int8_t* wbase = wpack
            + ((size_t)((j * 8 + wv * 2) * 4 + g) * 18) * 1024 + lane * 16;

        // depth-3 software-pipelined burst over 18 (t,ch) units
        int4v A0[3], A1[3], B0[3], B1[3];
#define LOADU(S, U) do { \
        A0[S] = *(const int4v*)(wbase + (U) * 1024); \
        A1[S] = *(const int4v*)(wbase + 73728 + (U) * 1024); \
        const int imm_ = ((U) & 1) * L_CH + (((U) >> 1) / 3) * L_ROW \
                       + (((U) >> 1) % 3) * L_PX; \
        B0[S] = *(const int4v*)(L + boff[0] + imm_); \
        B1[S] = *(const int4v*)(L + boff[1] + imm_); \
    } while (0)
#define MMAU(S) do { \
        MFMA_I8(acc[0][0], A0[S], B0[S]); \
        MFMA_I8(acc[0][1], A0[S], B1[S]); \
        MFMA_I8(acc[1][0], A1[S], B0[S]); \
        MFMA_I8(acc[1][1], A1[S], B1[S]); \
    } while (0)

        LOADU(0, 0); LOADU(1, 1); LOADU(2, 2);
        __builtin_amdgcn_s_setprio(1);
        MMAU(0); LOADU(0, 3);
        MMAU(1); LOADU(1, 4);
        MMAU(2); LOADU(2, 5);
        MMAU(0); LOADU(0, 6);
        MMAU(1); LOADU(1, 7);
        MMAU(2); LOADU(2, 8);
        MMAU(0); LOADU(0, 9);
        MMAU(1); LOADU(1, 10);
        MMAU(2); LOADU(2, 11);
        MMAU(0); LOADU(0, 12);
        MMAU(1); LOADU(1, 13);
        MMAU(2); LOADU(2, 14);
        MMAU(0); LOADU(0, 15);
        MMAU(1); LOADU(1, 16);
        MMAU(2); LOADU(2, 17);
        MMAU(0); MMAU(1); MMAU(2);
        __builtin_amdgcn_s_setprio(0);
#undef LOADU
#undef MMAU

        // write next tile into the other buffer
        if (ph < 11) stage_write(&lds[(ph + 1) & 1][0]);

        // fold at end of each j
        if ((ph & 3) == 3) {
            const float* scj = scales + j * CC + wv * 64;
            #pragma unroll
            for (int q = 0; q < 2; ++q) {
                #pragma unroll
                for (int r = 0; r < 16; ++r) {
                    const int rb = q * 32 + (r & 3) + 8 * (r >> 2);
                    const float slo = scj[rb], shi = scj[rb + 4];
                    const float sc = (lane & 32) ? shi : slo;
                    fsum[q][0][r] += sc * (float)acc[q][0][r];
                    fsum[q][1][r] += sc * (float)acc[q][1][r];
                }
            }
        }
        __syncthreads();
    }

    // epilogue (D layout: col=lane&31, row=(r&3)+8*(r>>2)+4*(lane>>5))
    const int voff = (lane & 31) + ((lane >> 5) & 1) * (4 * HH * WW);
    #pragma unroll
    for (int q = 0; q < 2; ++q) {
        #pragma unroll
        for (int r = 0; r < 16; ++r) {
            const int o_lo = wv * 64 + q * 32 + (r & 3) + 8 * (r >> 2);
            const float* elo = epack + o_lo * 4;
            const float* ehi = epack + (o_lo + 4) * 4;
            const bool hi = (lane & 32) != 0;
            const float e0 = hi ? ehi[0] : elo[0];
            const float e1 = hi ? ehi[1] : elo[1];
            const float e2 = hi ? ehi[2] : elo[2];
            const float e3 = hi ? ehi[3] : elo[3];
            const size_t base = ((size_t)n * CC + o_lo) * (HH * WW) + px0;
            #pragma unroll
            for (int pt = 0; pt < 2; ++pt) {
                const size_t off = base + pt * 32 + voff;
                float v = fsum[q][pt][r] * e0 + e1 + x[off];
                v = (v > 0.f) ? v : e2 * v;
                out[off] = v + e3;
            }
        }
    }
}

// ===========================================================================
extern "C" void kernel_launch(void* const* d_in, const int* in_sizes, int n_in,
                              void* d_out, int out_size, void* d_ws, size_t ws_size,
                              hipStream_t stream) {
    const float* x       = (const float*)d_in[0];
    const float* bias0   = (const float*)d_in[1];
    const float* w0      = (const float*)d_in[2];
    const float* w1      = (const float*)d_in[3];
    const float* w2      = (const float*)d_in[4];
    const float* gamma   = (const float*)d_in[5];
    const float* beta    = (const float*)d_in[6];
    const float* rmean   = (const float*)d_in[7];
    const float* rvar    = (const float*)d_in[8];
    const float* bias1   = (const float*)d_in[9];
    const float* prelu_a = (const float*)d_in[10];
    const float* bias2   = (const float*)d_in[11];
    float* out = (float*)d_out;

    int8_t* act8   = (int8_t*)d_ws;
    int8_t* wpack  = act8 + ACT8_BYTES;
    float*  scales = (float*)(wpack + WPACK_BYTES);
    float*  epack  = scales + NCONV * CC;

    pack_act8_kernel<<<dim3(BB * HH), dim3(256), 0, stream>>>(x, bias0, act8);
    pack_scales_kernel<<<dim3(NCONV * CC), dim3(64), 0, stream>>>(
        w0, w1, w2, scales, gamma, beta, rmean, rvar, bias1, prelu_a, bias2, epack);
    pack_wpack_kernel<<<dim3(NCONV * 8), dim3(256), 0, stream>>>(w0, w1, w2, wpack);
    conv_mfma_kernel<<<dim3(BB * 49), dim3(256), 0, stream>>>(
        act8, wpack, scales, epack, x, out);
}

// Round 8
// 264.424 us; speedup vs baseline: 1.6228x; 1.0408x over previous
//
#include <hip/hip_runtime.h>
#include <stdint.h>

#define BB 32
#define CC 256
#define HH 56
#define WW 56
#define TAPS 9
#define NCONV 3
#define BN_EPS 1e-5f

typedef int int4v  __attribute__((ext_vector_type(4)));
typedef int int16v __attribute__((ext_vector_type(16)));

// v_mfma_i32_32x32x32_i8: A 4 VGPR (16 i8), B 4 VGPR, C/D 16 VGPR.
#define MFMA_I8(accv, av, bv) \
    asm("v_mfma_i32_32x32x32_i8 %0, %1, %2, %0" : "+v"(accv) : "v"(av), "v"(bv))

// ---------------- workspace layout (bytes) ----------------
#define ACT8_BYTES   ((size_t)BB * HH * WW * CC)
#define WPACK_BYTES  ((size_t)NCONV * 8 * 4 * TAPS * 2 * 64 * 16)

// LDS act tile: ch-half planes, px stride 32B, XOR bank swizzle on bits 4-5.
#define L_PX   32
#define L_ROW  (58 * L_PX)        // 1856
#define L_CH   (4 * L_ROW)        // 7424
#define L_BUF  (2 * L_CH)         // 14848 per buffer
#define NSTU   (4 * 58 * 4)       // 928 16B staging units per tile
#define SWZ(c) ((((c) ^ ((c) >> 2)) & 3) << 4)

// act8[n][h][w][c] = sign(x + bias0) in i8. LDS transpose for coalescing.
__global__ __launch_bounds__(256) void pack_act8_kernel(
    const float* __restrict__ x, const float* __restrict__ bias0,
    int8_t* __restrict__ act8)
{
    __shared__ int8_t ldsT[56 * 260];
    const int tid = threadIdx.x;
    const int h = blockIdx.x % HH, n = blockIdx.x / HH;
    const int w = tid & 63;
    const int cq = tid >> 6;
    if (w < WW) {
        #pragma unroll 4
        for (int cc = 0; cc < 64; ++cc) {
            const int c = cc * 4 + cq;
            const float v = x[((size_t)(n * CC + c) * HH + h) * WW + w] + bias0[c];
            ldsT[w * 260 + c] = (v > 0.f) ? (int8_t)1 : ((v < 0.f) ? (int8_t)-1 : (int8_t)0);
        }
    }
    __syncthreads();
    uint32_t* o32 = (uint32_t*)(act8 + (size_t)(n * HH + h) * WW * CC);
    #pragma unroll
    for (int i = 0; i < 14; ++i) {
        const int flat = i * 1024 + tid * 4;
        const int ww = flat >> 8, c4 = flat & 255;
        o32[flat >> 2] = *(const uint32_t*)(ldsT + ww * 260 + c4);
    }
}

// per-output-channel scale = mean |w| (one wave per (j,o)); epack fused in.
__global__ __launch_bounds__(64) void pack_scales_kernel(
    const float* __restrict__ w0, const float* __restrict__ w1,
    const float* __restrict__ w2, float* __restrict__ scales,
    const float* __restrict__ gamma, const float* __restrict__ beta,
    const float* __restrict__ rmean, const float* __restrict__ rvar,
    const float* __restrict__ bias1, const float* __restrict__ prelu_a,
    const float* __restrict__ bias2, float* __restrict__ epack)
{
    const int j = blockIdx.x >> 8;
    const int o = blockIdx.x & 255;
    const float* wp = (j == 0) ? w0 : ((j == 1) ? w1 : w2);
    const int lane = threadIdx.x;
    const float* wo = wp + (size_t)o * CC * TAPS;
    float s = 0.f;
    for (int k = lane; k < CC * TAPS; k += 64) s += fabsf(wo[k]);
    #pragma unroll
    for (int d = 32; d > 0; d >>= 1) s += __shfl_xor(s, d);
    if (lane == 0) scales[j * CC + o] = s * (1.0f / (float)(CC * TAPS));
    if (j == 0 && lane == 0) {
        const float A = gamma[o] * rsqrtf(rvar[o] + BN_EPS);
        epack[o * 4 + 0] = A;
        epack[o * 4 + 1] = beta[o] - rmean[o] * A + bias1[o];
        epack[o * 4 + 2] = prelu_a[o];
        epack[o * 4 + 3] = bias2[o];
    }
}

// weight signs in exact A-fragment order (verified r5-r7).
__global__ __launch_bounds__(256) void pack_wpack_kernel(
    const float* __restrict__ w0, const float* __restrict__ w1,
    const float* __restrict__ w2, int8_t* __restrict__ wpack)
{
    const int j  = blockIdx.x >> 3;
    const int ot = blockIdx.x & 7;
    const float* wp = (j == 0) ? w0 : ((j == 1) ? w1 : w2);
    const int tid = threadIdx.x;
    #pragma unroll 1
    for (int it = 0; it < 18; ++it) {
        const int e = it * 256 + tid;
        const int g = e / 1152;
        const int rem = e - g * 1152;
        const int tt = rem >> 7;
        const int rem2 = rem & 127;
        const int ch = rem2 >> 6;
        const int ln = rem2 & 63;
        const int o = ot * 32 + (ln & 31);
        const int cbase = g * 64 + ch * 32 + ((ln >> 5) & 1) * 16;
        int8_t bytes[16];
        #pragma unroll
        for (int b = 0; b < 16; ++b) {
            const float v = wp[((size_t)o * CC + cbase + b) * TAPS + tt];
            bytes[b] = (v > 0.f) ? (int8_t)1 : ((v < 0.f) ? (int8_t)-1 : (int8_t)0);
        }
        *(int4v*)(wpack + ((size_t)(j * 8 + ot) * 4608 + e) * 16) = *(int4v*)bytes;
    }
}

// main: i8 MFMA implicit conv; dbuf LDS staging; A depth-5 / B depth-3 reg
// rings; next-phase A-prologue hoisted before the barrier; XOR bank swizzle.
__global__ __launch_bounds__(256) void conv_mfma_kernel(
    const int8_t* __restrict__ act8, const int8_t* __restrict__ wpack,
    const float* __restrict__ scales, const float* __restrict__ epack,
    const float* __restrict__ x, float* __restrict__ out)
{
    __shared__ __align__(16) int8_t lds[2][L_BUF];
    const int tid  = threadIdx.x;
    const int lane = tid & 63;
    const int wv   = __builtin_amdgcn_readfirstlane(tid >> 6);
    const int bid  = blockIdx.x;
    const int swz  = (bid & 7) * 196 + (bid >> 3);   // bijective: 1568 = 8*196
    const int pxblk = swz % 49;
    const int n     = swz / 49;
    const int px0   = pxblk * 64;
    const int h_lo  = px0 / WW;

    // per-lane swizzled LDS bases: [px tile][tap col]
    int boff2[2][3];
    #pragma unroll
    for (int pt = 0; pt < 2; ++pt) {
        const int p = px0 + pt * 32 + (lane & 31);
        const int hl = p / WW, wl = p % WW;
        #pragma unroll
        for (int tc = 0; tc < 3; ++tc) {
            const int col = wl + tc;
            const int a = (hl - h_lo) * L_ROW + col * L_PX + ((lane >> 5) & 1) * 16;
            boff2[pt][tc] = a ^ SWZ(col);
        }
    }
    const size_t nbase = (size_t)n * HH;

    float fsum[2][2][16];
    #pragma unroll
    for (int q = 0; q < 2; ++q)
        #pragma unroll
        for (int pt = 0; pt < 2; ++pt)
            #pragma unroll
            for (int r = 0; r < 16; ++r) fsum[q][pt][r] = 0.f;

    int16v acc[2][2];
    int4v sreg[4];
    int4v A0[5], A1[5], B0[3], B1[3];

    auto stage_load = [&](int rH, int rW, int gg) {
        #pragma unroll
        for (int k = 0; k < 4; ++k) {
            const int u = tid + k * 256;
            int4v v = {0, 0, 0, 0};
            if (u < NSTU) {
                const int r = u / 232;
                const int rem = u - r * 232;
                const int c = rem >> 2, q = rem & 3;
                const int hr = h_lo - 1 + r, wc = c - 1;
                if (hr >= 0 && hr < HH && wc >= 0 && wc < WW) {
                    int hs = hr + rH; if (hs < 0) hs += HH; else if (hs >= HH) hs -= HH;
                    int ws = wc + rW; if (ws < 0) ws += WW; else if (ws >= WW) ws -= WW;
                    v = *(const int4v*)(act8 +
                        (((nbase + hs) * WW + ws) << 8) + gg * 64 + q * 16);
                }
            }
            sreg[k] = v;
        }
    };
    auto stage_write = [&](int8_t* Ln) {
        #pragma unroll
        for (int k = 0; k < 4; ++k) {
            const int u = tid + k * 256;
            if (u < NSTU) {
                const int r = u / 232;
                const int rem = u - r * 232;
                const int c = rem >> 2, q = rem & 3;
                int a = (q >> 1) * L_CH + r * L_ROW + c * L_PX + (q & 1) * 16;
                a ^= SWZ(c);
                *(int4v*)(Ln + a) = sreg[k];
            }
        }
    };

#define LDA_P(W, S, U) do { \
        A0[S] = *(const int4v*)((W) + (U) * 1024); \
        A1[S] = *(const int4v*)((W) + 73728 + (U) * 1024); } while (0)
#define LDB_P(S, U) do { \
        const int imm_ = ((U) & 1) * L_CH + (((U) >> 1) / 3) * L_ROW; \
        const int tc_ = ((U) >> 1) % 3; \
        B0[S] = *(const int4v*)(L + boff2[0][tc_] + imm_); \
        B1[S] = *(const int4v*)(L + boff2[1][tc_] + imm_); } while (0)
#define MMX(SA, SB) do { \
        MFMA_I8(acc[0][0], A0[SA], B0[SB]); \
        MFMA_I8(acc[0][1], A0[SA], B1[SB]); \
        MFMA_I8(acc[1][0], A1[SA], B0[SB]); \
        MFMA_I8(acc[1][1], A1[SA], B1[SB]); } while (0)

    // ---- prologue: stage phase 0 (j=0 no roll, g=0); preload A units 0..4 ----
    stage_load(0, 0, 0);
    stage_write(&lds[0][0]);
    {
        const int8_t* w0b = wpack + ((size_t)((0 * 8 + wv * 2) * 4 + 0) * 18) * 1024 + lane * 16;
        LDA_P(w0b, 0, 0); LDA_P(w0b, 1, 1); LDA_P(w0b, 2, 2);
        LDA_P(w0b, 3, 3); LDA_P(w0b, 4, 4);
    }
    __syncthreads();

    #pragma unroll 1
    for (int ph = 0; ph < 12; ++ph) {
        const int j = ph >> 2, g = ph & 3;
        if ((ph & 3) == 0) {
            #pragma unroll
            for (int q = 0; q < 2; ++q)
                #pragma unroll
                for (int pt = 0; pt < 2; ++pt)
                    #pragma unroll
                    for (int r = 0; r < 16; ++r) acc[q][pt][r] = 0;
        }

        const int8_t* L = &lds[ph & 1][0];
        const int8_t* wbase = wpack
            + ((size_t)((j * 8 + wv * 2) * 4 + g) * 18) * 1024 + lane * 16;

        // B prologue (buffer valid post-barrier)
        LDB_P(0, 0); LDB_P(1, 1); LDB_P(2, 2);

        // prefetch next phase act tile into regs (GATHER roll: src[idx-amt])
        if (ph < 11) {
            const int ph2 = ph + 1;
            const int j2 = ph2 >> 2, g2 = ph2 & 3;
            const int amt2 = (j2 == 0) ? 0 : ((j2 == 1) ? 1 : 3);
            const int rH = (g2 == 0) ? -amt2 : ((g2 == 1) ? amt2 : 0);
            const int rW = (g2 == 2) ? -amt2 : ((g2 == 3) ? amt2 : 0);
            stage_load(rH, rW, g2);
        }

        __builtin_amdgcn_s_setprio(1);
        MMX(0, 0); LDA_P(wbase, 0, 5);  LDB_P(0, 3);
        MMX(1, 1); LDA_P(wbase, 1, 6);  LDB_P(1, 4);
        MMX(2, 2); LDA_P(wbase, 2, 7);  LDB_P(2, 5);
        MMX(3, 0); LDA_P(wbase, 3, 8);  LDB_P(0, 6);
        MMX(4, 1); LDA_P(wbase, 4, 9);  LDB_P(1, 7);
        MMX(0, 2); LDA_P(wbase, 0, 10); LDB_P(2, 8);
        MMX(1, 0); LDA_P(wbase, 1, 11); LDB_P(0, 9);
        MMX(2, 1); LDA_P(wbase, 2, 12); LDB_P(1, 10);
        MMX(3, 2); LDA_P(wbase, 3, 13); LDB_P(2, 11);
        MMX(4, 0); LDA_P(wbase, 4, 14); LDB_P(0, 12);
        MMX(0, 1); LDA_P(wbase, 0, 15); LDB_P(1, 13);
        MMX(1, 2); LDA_P(wbase, 1, 16); LDB_P(2, 14);
        MMX(2, 0); LDA_P(wbase, 2, 17); LDB_P(0, 15);
        MMX(3, 1); LDB_P(1, 16);
        MMX(4, 2); LDB_P(2, 17);
        MMX(0, 0);
        MMX(1, 1);
        MMX(2, 2);
        __builtin_amdgcn_s_setprio(0);

        // hoisted A prologue for next phase (no LDS dependency)
        if (ph < 11) {
            const int ph2 = ph + 1;
            const int j2 = ph2 >> 2, g2 = ph2 & 3;
            const int8_t* wnext = wpack
                + ((size_t)((j2 * 8 + wv * 2) * 4 + g2) * 18) * 1024 + lane * 16;
            LDA_P(wnext, 0, 0); LDA_P(wnext, 1, 1); LDA_P(wnext, 2, 2);
            LDA_P(wnext, 3, 3); LDA_P(wnext, 4, 4);
        }

        // write next act tile into the other buffer
        if (ph < 11) stage_write(&lds[(ph + 1) & 1][0]);

        // fold at end of each j
        if ((ph & 3) == 3) {
            const float* scj = scales + j * CC + wv * 64;
            #pragma unroll
            for (int q = 0; q < 2; ++q) {
                #pragma unroll
                for (int r = 0; r < 16; ++r) {
                    const int rb = q * 32 + (r & 3) + 8 * (r >> 2);
                    const float slo = scj[rb], shi = scj[rb + 4];
                    const float sc = (lane & 32) ? shi : slo;
                    fsum[q][0][r] += sc * (float)acc[q][0][r];
                    fsum[q][1][r] += sc * (float)acc[q][1][r];
                }
            }
        }
        __syncthreads();
    }
#undef LDA_P
#undef LDB_P
#undef MMX

    // epilogue (D layout: col=lane&31, row=(r&3)+8*(r>>2)+4*(lane>>5))
    const int voff = (lane & 31) + ((lane >> 5) & 1) * (4 * HH * WW);
    #pragma unroll
    for (int q = 0; q < 2; ++q) {
        #pragma unroll
        for (int r = 0; r < 16; ++r) {
            const int o_lo = wv * 64 + q * 32 + (r & 3) + 8 * (r >> 2);
            const float* elo = epack + o_lo * 4;
            const float* ehi = epack + (o_lo + 4) * 4;
            const bool hi = (lane & 32) != 0;
            const float e0 = hi ? ehi[0] : elo[0];
            const float e1 = hi ? ehi[1] : elo[1];
            const float e2 = hi ? ehi[2] : elo[2];
            const float e3 = hi ? ehi[3] : elo[3];
            const size_t base = ((size_t)n * CC + o_lo) * (HH * WW) + px0;
            #pragma unroll
            for (int pt = 0; pt < 2; ++pt) {
                const size_t off = base + pt * 32 + voff;
                float v = fsum[q][pt][r] * e0 + e1 + x[off];
                v = (v > 0.f) ? v : e2 * v;
                out[off] = v + e3;
            }
        }
    }
}

// ===========================================================================
extern "C" void kernel_launch(void* const* d_in, const int* in_sizes, int n_in,
                              void* d_out, int out_size, void* d_ws, size_t ws_size,
                              hipStream_t stream) {
    const float* x       = (const float*)d_in[0];
    const float* bias0   = (const float*)d_in[1];
    const float* w0      = (const float*)d_in[2];
    const float* w1      = (const float*)d_in[3];
    const float* w2      = (const float*)d_in[4];
    const float* gamma   = (const float*)d_in[5];
    const float* beta    = (const float*)d_in[6];
    const float* rmean   = (const float*)d_in[7];
    const float* rvar    = (const float*)d_in[8];
    const float* bias1   = (const float*)d_in[9];
    const float* prelu_a = (const float*)d_in[10];
    const float* bias2   = (const float*)d_in[11];
    float* out = (float*)d_out;

    int8_t* act8   = (int8_t*)d_ws;
    int8_t* wpack  = act8 + ACT8_BYTES;
    float*  scales = (float*)(wpack + WPACK_BYTES);
    float*  epack  = scales + NCONV * CC;

    pack_act8_kernel<<<dim3(BB * HH), dim3(256), 0, stream>>>(x, bias0, act8);
    pack_scales_kernel<<<dim3(NCONV * CC), dim3(64), 0, stream>>>(
        w0, w1, w2, scales, gamma, beta, rmean, rvar, bias1, prelu_a, bias2, epack);
    pack_wpack_kernel<<<dim3(NCONV * 8), dim3(256), 0, stream>>>(w0, w1, w2, wpack);
    conv_mfma_kernel<<<dim3(BB * 49), dim3(256), 0, stream>>>(
        act8, wpack, scales, epack, x, out);
}